// Round 1
// baseline (1767.167 us; speedup 1.0000x reference)
//
#include <hip/hip_runtime.h>

#define HID 16
#define ODIM 64
#define IDIM 512

// ---------------------------------------------------------------- deg kernels
__global__ void k_init_deg(int* __restrict__ deg, int n) {
    int i = blockIdx.x * blockDim.x + threadIdx.x;
    if (i < n) deg[i] = 1;  // self loop
}

__global__ void k_count_deg(const int* __restrict__ dst, int* __restrict__ deg, int ne) {
    int e = blockIdx.x * blockDim.x + threadIdx.x;
    if (e < ne) atomicAdd(&deg[dst[e]], 1);
}

// ------------------------------------------------- layer1 projection: X @ W1
// thread-per-node; W1 (512x16) staged in LDS (32 KB); writes hs1 = (X@W1)*dinv
// into B1 and the same value into B2 as the self-loop-initialized accumulator.
__global__ __launch_bounds__(256) void k_proj1(const float* __restrict__ X,
                                               const float* __restrict__ W1,
                                               const int* __restrict__ deg,
                                               float* __restrict__ hs1,
                                               float* __restrict__ agg1, int n) {
    __shared__ float Ws[IDIM * HID];
    for (int t = threadIdx.x; t < IDIM * HID; t += 256) Ws[t] = W1[t];
    __syncthreads();

    int i = blockIdx.x * blockDim.x + threadIdx.x;
    if (i >= n) return;

    const float4* xr = (const float4*)(X + (size_t)i * IDIM);
    float acc[HID];
#pragma unroll
    for (int j = 0; j < HID; ++j) acc[j] = 0.f;

    for (int k4 = 0; k4 < IDIM / 4; ++k4) {
        float4 x = xr[k4];
        const float* w = &Ws[k4 * 4 * HID];
#pragma unroll
        for (int j = 0; j < HID; ++j) acc[j] += x.x * w[j];
#pragma unroll
        for (int j = 0; j < HID; ++j) acc[j] += x.y * w[HID + j];
#pragma unroll
        for (int j = 0; j < HID; ++j) acc[j] += x.z * w[2 * HID + j];
#pragma unroll
        for (int j = 0; j < HID; ++j) acc[j] += x.w * w[3 * HID + j];
    }

    float di = rsqrtf((float)deg[i]);
    float4* h4 = (float4*)(hs1 + (size_t)i * HID);
    float4* a4 = (float4*)(agg1 + (size_t)i * HID);
#pragma unroll
    for (int q = 0; q < 4; ++q) {
        float4 v;
        v.x = acc[q * 4 + 0] * di;
        v.y = acc[q * 4 + 1] * di;
        v.z = acc[q * 4 + 2] * di;
        v.w = acc[q * 4 + 3] * di;
        h4[q] = v;
        a4[q] = v;
    }
}

// --------------------------------------------------- edge scatter (16 floats)
// 4 lanes per edge, float4 gather from hs[src], 4 f32 atomics into agg[dst].
__global__ __launch_bounds__(256) void k_edge(const int* __restrict__ src,
                                              const int* __restrict__ dst,
                                              const float* __restrict__ hs,
                                              float* __restrict__ agg, int ne) {
    int tid = blockIdx.x * blockDim.x + threadIdx.x;
    int e = tid >> 2;
    int q = tid & 3;
    if (e >= ne) return;
    int s = src[e];
    int d = dst[e];
    float4 v = *(const float4*)(hs + (size_t)s * HID + q * 4);
    float* o = agg + (size_t)d * HID + q * 4;
    atomicAdd(o + 0, v.x);
    atomicAdd(o + 1, v.y);
    atomicAdd(o + 2, v.z);
    atomicAdd(o + 3, v.w);
}

// ------------------------------------------ finalize L1 + prep L2 aggregation
// H = relu(dinv*agg1 + b1); hs2 = H*dinv; agg1 buffer becomes hs2 (in-place),
// agg2 buffer (old hs1) gets the self-loop init value hs2.
__global__ void k_mid(const int* __restrict__ deg, const float* __restrict__ b1,
                      float* __restrict__ agg1_hs2, float* __restrict__ agg2, int n) {
    int t = blockIdx.x * blockDim.x + threadIdx.x;
    if (t >= n * HID) return;
    int i = t >> 4;
    int j = t & 15;
    float di = rsqrtf((float)deg[i]);
    float h = di * agg1_hs2[t] + b1[j];
    h = fmaxf(h, 0.f);
    float v = h * di;
    agg1_hs2[t] = v;
    agg2[t] = v;
}

// ----------------------------------------------- output projection g @ W2 + b
// 64 threads per node (whole wave shares one node -> broadcast g reads).
__global__ __launch_bounds__(256) void k_out(const int* __restrict__ deg,
                                             const float* __restrict__ agg2,
                                             const float* __restrict__ W2,
                                             const float* __restrict__ b2,
                                             float* __restrict__ out, int n) {
    __shared__ float Ws[HID * ODIM];
    __shared__ float bs[ODIM];
    for (int t = threadIdx.x; t < HID * ODIM; t += 256) Ws[t] = W2[t];
    if (threadIdx.x < ODIM) bs[threadIdx.x] = b2[threadIdx.x];
    __syncthreads();

    int t = blockIdx.x * blockDim.x + threadIdx.x;
    if (t >= n * ODIM) return;
    int i = t >> 6;
    int j = t & 63;
    float di = rsqrtf((float)deg[i]);
    const float* g = agg2 + (size_t)i * HID;
    float acc = 0.f;
#pragma unroll
    for (int k = 0; k < HID; ++k) acc += g[k] * Ws[k * ODIM + j];
    out[t] = di * acc + bs[j];
}

// ---------------------------------------------------------------------- launch
extern "C" void kernel_launch(void* const* d_in, const int* in_sizes, int n_in,
                              void* d_out, int out_size, void* d_ws, size_t ws_size,
                              hipStream_t stream) {
    const int* E = (const int*)d_in[1];
    const float* X = (const float*)d_in[2];
    const float* W1 = (const float*)d_in[3];
    const float* b1 = (const float*)d_in[4];
    const float* W2 = (const float*)d_in[5];
    const float* b2 = (const float*)d_in[6];
    float* out = (float*)d_out;

    const int n = in_sizes[0];       // 100000
    const int ne = in_sizes[1] / 2;  // 3200000
    const int* src = E;
    const int* dst = E + ne;

    // workspace layout: deg (int, 400 KB) | B1 @1MB (hs1 -> agg2) | B2 @8MB (agg1 -> hs2)
    char* ws = (char*)d_ws;
    int* deg = (int*)ws;
    float* B1 = (float*)(ws + (1u << 20));
    float* B2 = (float*)(ws + (8u << 20));

    k_init_deg<<<(n + 255) / 256, 256, 0, stream>>>(deg, n);
    k_count_deg<<<(ne + 255) / 256, 256, 0, stream>>>(dst, deg, ne);
    k_proj1<<<(n + 255) / 256, 256, 0, stream>>>(X, W1, deg, B1, B2, n);
    k_edge<<<(ne * 4 + 255) / 256, 256, 0, stream>>>(src, dst, B1, B2, ne);
    k_mid<<<(n * HID + 255) / 256, 256, 0, stream>>>(deg, b1, B2, B1, n);
    k_edge<<<(ne * 4 + 255) / 256, 256, 0, stream>>>(src, dst, B2, B1, ne);
    k_out<<<(n * ODIM + 255) / 256, 256, 0, stream>>>(deg, B1, W2, b2, out, n);
}

// Round 2
// 1078.674 us; speedup vs baseline: 1.6383x; 1.6383x over previous
//
#include <hip/hip_runtime.h>

#define HID 16
#define ODIM 64
#define IDIM 512

// ------------------------------------------------------------ CSR build chain
__global__ void k_zero_cnt(int* __restrict__ cnt, int n) {
    int i = blockIdx.x * blockDim.x + threadIdx.x;
    if (i < n) cnt[i] = 0;
}

__global__ void k_count(const int* __restrict__ dst, int* __restrict__ cnt, int ne) {
    int e = blockIdx.x * blockDim.x + threadIdx.x;
    if (e < ne) atomicAdd(&cnt[dst[e]], 1);
}

// single-block exclusive scan over cnt -> row_start, cursor (copy)
__global__ __launch_bounds__(1024) void k_scan(const int* __restrict__ cnt,
                                               int* __restrict__ row_start,
                                               int* __restrict__ cursor, int n) {
    __shared__ int sums[1024];
    int tid = threadIdx.x;
    int chunk = (n + 1023) / 1024;
    int begin = tid * chunk;
    int end = begin + chunk;
    if (end > n) end = n;
    int s = 0;
    for (int i = begin; i < end; ++i) s += cnt[i];
    sums[tid] = s;
    __syncthreads();
    for (int off = 1; off < 1024; off <<= 1) {
        int v = 0;
        if (tid >= off) v = sums[tid - off];
        __syncthreads();
        if (tid >= off) sums[tid] += v;
        __syncthreads();
    }
    int run = (tid > 0) ? sums[tid - 1] : 0;
    for (int i = begin; i < end; ++i) {
        row_start[i] = run;
        cursor[i] = run;
        run += cnt[i];
    }
}

__global__ void k_fill(const int* __restrict__ src, const int* __restrict__ dst,
                       int* __restrict__ cursor, int* __restrict__ csr_src, int ne) {
    int e = blockIdx.x * blockDim.x + threadIdx.x;
    if (e >= ne) return;
    int p = atomicAdd(&cursor[dst[e]], 1);
    csr_src[p] = src[e];
}

// ------------------------------------------------- layer1 projection: X @ W1
// thread-per-node; W1 (512x16) in LDS; writes hs1 = (X@W1)*dinv only.
__global__ __launch_bounds__(256) void k_proj1(const float* __restrict__ X,
                                               const float* __restrict__ W1,
                                               const int* __restrict__ cnt,
                                               float* __restrict__ hs1, int n) {
    __shared__ float Ws[IDIM * HID];
    for (int t = threadIdx.x; t < IDIM * HID; t += 256) Ws[t] = W1[t];
    __syncthreads();

    int i = blockIdx.x * blockDim.x + threadIdx.x;
    if (i >= n) return;

    const float4* xr = (const float4*)(X + (size_t)i * IDIM);
    float acc[HID];
#pragma unroll
    for (int j = 0; j < HID; ++j) acc[j] = 0.f;

    for (int k4 = 0; k4 < IDIM / 4; ++k4) {
        float4 x = xr[k4];
        const float* w = &Ws[k4 * 4 * HID];
#pragma unroll
        for (int j = 0; j < HID; ++j) acc[j] += x.x * w[j];
#pragma unroll
        for (int j = 0; j < HID; ++j) acc[j] += x.y * w[HID + j];
#pragma unroll
        for (int j = 0; j < HID; ++j) acc[j] += x.z * w[2 * HID + j];
#pragma unroll
        for (int j = 0; j < HID; ++j) acc[j] += x.w * w[3 * HID + j];
    }

    float di = rsqrtf((float)(cnt[i] + 1));
    float4* h4 = (float4*)(hs1 + (size_t)i * HID);
#pragma unroll
    for (int q = 0; q < 4; ++q) {
        float4 v;
        v.x = acc[q * 4 + 0] * di;
        v.y = acc[q * 4 + 1] * di;
        v.z = acc[q * 4 + 2] * di;
        v.w = acc[q * 4 + 3] * di;
        h4[q] = v;
    }
}

// ------------------------------------------- atomic-free aggregation via CSR
// 4 lanes per node; lane q owns float4 chunk q of the 16-dim row.
// acc initialized from own row (self loop), then sum over incoming edges.
__global__ __launch_bounds__(256) void k_gather(const int* __restrict__ row_start,
                                                const int* __restrict__ cnt,
                                                const int* __restrict__ csr_src,
                                                const float* __restrict__ hs,
                                                float* __restrict__ agg, int n) {
    int tid = blockIdx.x * blockDim.x + threadIdx.x;
    int i = tid >> 2;
    int q = tid & 3;
    if (i >= n) return;
    int rs = row_start[i];
    int c = cnt[i];
    const float4* h4 = (const float4*)hs;
    float4 acc = h4[(size_t)i * 4 + q];  // self loop
    int k = 0;
    for (; k + 1 < c; k += 2) {
        int s0 = csr_src[rs + k];
        int s1 = csr_src[rs + k + 1];
        float4 v0 = h4[(size_t)s0 * 4 + q];
        float4 v1 = h4[(size_t)s1 * 4 + q];
        acc.x += v0.x; acc.y += v0.y; acc.z += v0.z; acc.w += v0.w;
        acc.x += v1.x; acc.y += v1.y; acc.z += v1.z; acc.w += v1.w;
    }
    if (k < c) {
        int s0 = csr_src[rs + k];
        float4 v0 = h4[(size_t)s0 * 4 + q];
        acc.x += v0.x; acc.y += v0.y; acc.z += v0.z; acc.w += v0.w;
    }
    ((float4*)agg)[(size_t)i * 4 + q] = acc;
}

// --------------------------- finalize L1 + rescale for L2 (in-place, per elem)
__global__ void k_mid(const int* __restrict__ cnt, const float* __restrict__ b1,
                      float* __restrict__ buf, int n) {
    int t = blockIdx.x * blockDim.x + threadIdx.x;
    if (t >= n * HID) return;
    int i = t >> 4;
    int j = t & 15;
    float di = rsqrtf((float)(cnt[i] + 1));
    float h = di * buf[t] + b1[j];
    h = fmaxf(h, 0.f);
    buf[t] = h * di;
}

// ----------------------------------------------- output projection g @ W2 + b
__global__ __launch_bounds__(256) void k_out(const int* __restrict__ cnt,
                                             const float* __restrict__ agg2,
                                             const float* __restrict__ W2,
                                             const float* __restrict__ b2,
                                             float* __restrict__ out, int n) {
    __shared__ float Ws[HID * ODIM];
    __shared__ float bs[ODIM];
    for (int t = threadIdx.x; t < HID * ODIM; t += 256) Ws[t] = W2[t];
    if (threadIdx.x < ODIM) bs[threadIdx.x] = b2[threadIdx.x];
    __syncthreads();

    int t = blockIdx.x * blockDim.x + threadIdx.x;
    if (t >= n * ODIM) return;
    int i = t >> 6;
    int j = t & 63;
    float di = rsqrtf((float)(cnt[i] + 1));
    const float* g = agg2 + (size_t)i * HID;
    float acc = 0.f;
#pragma unroll
    for (int k = 0; k < HID; ++k) acc += g[k] * Ws[k * ODIM + j];
    out[t] = di * acc + bs[j];
}

// ---------------------------------------------------------------------- launch
extern "C" void kernel_launch(void* const* d_in, const int* in_sizes, int n_in,
                              void* d_out, int out_size, void* d_ws, size_t ws_size,
                              hipStream_t stream) {
    const int* E = (const int*)d_in[1];
    const float* X = (const float*)d_in[2];
    const float* W1 = (const float*)d_in[3];
    const float* b1 = (const float*)d_in[4];
    const float* W2 = (const float*)d_in[5];
    const float* b2 = (const float*)d_in[6];
    float* out = (float*)d_out;

    const int n = in_sizes[0];       // 100000
    const int ne = in_sizes[1] / 2;  // 3200000
    const int* src = E;
    const int* dst = E + ne;

    // workspace layout (bytes):
    //   cnt       @ 0        (400 KB)
    //   row_start @ 1 MB     (400 KB)
    //   cursor    @ 2 MB     (400 KB)
    //   csr_src   @ 3 MB     (12.8 MB)
    //   B1        @ 16 MB    (6.4 MB)  hs1 -> agg2
    //   B2        @ 24 MB    (6.4 MB)  agg1 -> hs2 (in-place)
    char* ws = (char*)d_ws;
    int* cnt = (int*)ws;
    int* row_start = (int*)(ws + (1u << 20));
    int* cursor = (int*)(ws + (2u << 20));
    int* csr_src = (int*)(ws + (3u << 20));
    float* B1 = (float*)(ws + (16u << 20));
    float* B2 = (float*)(ws + (24u << 20));

    k_zero_cnt<<<(n + 255) / 256, 256, 0, stream>>>(cnt, n);
    k_count<<<(ne + 255) / 256, 256, 0, stream>>>(dst, cnt, ne);
    k_scan<<<1, 1024, 0, stream>>>(cnt, row_start, cursor, n);
    k_fill<<<(ne + 255) / 256, 256, 0, stream>>>(src, dst, cursor, csr_src, ne);

    k_proj1<<<(n + 255) / 256, 256, 0, stream>>>(X, W1, cnt, B1, n);
    k_gather<<<(n * 4 + 255) / 256, 256, 0, stream>>>(row_start, cnt, csr_src, B1, B2, n);
    k_mid<<<(n * HID + 255) / 256, 256, 0, stream>>>(cnt, b1, B2, n);
    k_gather<<<(n * 4 + 255) / 256, 256, 0, stream>>>(row_start, cnt, csr_src, B2, B1, n);
    k_out<<<(n * ODIM + 255) / 256, 256, 0, stream>>>(cnt, B1, W2, b2, out, n);
}

// Round 3
// 555.950 us; speedup vs baseline: 3.1786x; 1.9402x over previous
//
#include <hip/hip_runtime.h>

#define HID 16
#define ODIM 64
#define IDIM 512
#define BKB 8          // bucket = 256 nodes (dst >> 8)
#define BKS 256
#define PTILE 4096     // edges per partition tile
#define MAXBE 12288    // LDS staging capacity per bucket (avg 8192, 45 sigma)

// ---------------------------------------------------- bucket histogram (dst>>8)
__global__ __launch_bounds__(256) void k_bhist(const int* __restrict__ dst,
                                               int* __restrict__ bcnt, int ne, int nbk) {
    __shared__ int h[512];
    for (int t = threadIdx.x; t < 512; t += 256) h[t] = 0;
    __syncthreads();
    int stride = gridDim.x * blockDim.x;
    for (int e = blockIdx.x * blockDim.x + threadIdx.x; e < ne; e += stride)
        atomicAdd(&h[dst[e] >> BKB], 1);
    __syncthreads();
    for (int t = threadIdx.x; t < nbk; t += 256)
        if (h[t]) atomicAdd(&bcnt[t], h[t]);
}

// ------------------------------------------------- scan bucket counts (nbk<=512)
__global__ __launch_bounds__(512) void k_bscan(const int* __restrict__ bcnt,
                                               int* __restrict__ bbase,
                                               int* __restrict__ bcur, int nbk) {
    __shared__ int s[512];
    int t = threadIdx.x;
    int v = (t < nbk) ? bcnt[t] : 0;
    s[t] = v;
    __syncthreads();
    for (int off = 1; off < 512; off <<= 1) {
        int u = (t >= off) ? s[t - off] : 0;
        __syncthreads();
        s[t] += u;
        __syncthreads();
    }
    if (t < nbk) { int b = s[t] - v; bbase[t] = b; bcur[t] = b; }
}

// ------------------------------------- partition edges into buckets (staged LDS)
// packed entry: (src << 8) | (dst & 255);  src < 2^17 so fits u32.
__global__ __launch_bounds__(512) void k_part(const int* __restrict__ src,
                                              const int* __restrict__ dst,
                                              int* __restrict__ bcur,
                                              unsigned int* __restrict__ ebuf,
                                              int ne, int nbk) {
    __shared__ int h[512], sc[512], base[512], lcur[512];
    __shared__ unsigned int sval[PTILE];
    __shared__ int saddr[PTILE];
    int e0 = blockIdx.x * PTILE;
    int m = ne - e0; if (m > PTILE) m = PTILE;
    if (m <= 0) return;
    int t = threadIdx.x;
    h[t] = 0;
    __syncthreads();
    for (int k = t; k < m; k += 512) atomicAdd(&h[dst[e0 + k] >> BKB], 1);
    __syncthreads();
    int hv = h[t];
    sc[t] = hv;
    __syncthreads();
    for (int off = 1; off < 512; off <<= 1) {
        int u = (t >= off) ? sc[t - off] : 0;
        __syncthreads();
        sc[t] += u;
        __syncthreads();
    }
    base[t] = hv ? atomicAdd(&bcur[t], hv) : 0;
    lcur[t] = 0;
    __syncthreads();
    for (int k = t; k < m; k += 512) {
        int d = dst[e0 + k];
        int b = d >> BKB;
        int r = atomicAdd(&lcur[b], 1);
        int slot = sc[b] - h[b] + r;              // tile-local bucket run
        sval[slot] = ((unsigned int)src[e0 + k] << BKB) | (unsigned int)(d & (BKS - 1));
        saddr[slot] = base[b] + r;                // global dest (bucket-grouped)
    }
    __syncthreads();
    for (int k = t; k < m; k += 512) ebuf[saddr[k]] = sval[k];
}

// ------------------- per-bucket CSR build in LDS: cnt, row_start, csr_src out
__global__ __launch_bounds__(256) void k_csr(const int* __restrict__ bbase,
                                             const int* __restrict__ bcnt,
                                             const unsigned int* __restrict__ ebuf,
                                             int* __restrict__ cnt,
                                             int* __restrict__ row_start,
                                             int* __restrict__ csr_src, int n) {
    __shared__ int h[256], sc[256], lc[256];
    __shared__ int stage[MAXBE];
    int bk = blockIdx.x;
    int node0 = bk << BKB;
    int ebase = bbase[bk];
    int ecnt = bcnt[bk];
    int t = threadIdx.x;
    h[t] = 0; lc[t] = 0;
    __syncthreads();
    for (int k = t; k < ecnt; k += 256) atomicAdd(&h[ebuf[ebase + k] & (BKS - 1)], 1);
    __syncthreads();
    int hv = h[t];
    sc[t] = hv;
    __syncthreads();
    for (int off = 1; off < 256; off <<= 1) {
        int u = (t >= off) ? sc[t - off] : 0;
        __syncthreads();
        sc[t] += u;
        __syncthreads();
    }
    int node = node0 + t;
    if (node < n) { cnt[node] = hv; row_start[node] = ebase + sc[t] - hv; }
    if (ecnt <= MAXBE) {
        for (int k = t; k < ecnt; k += 256) {
            unsigned int p = ebuf[ebase + k];
            int dl = p & (BKS - 1);
            int r = atomicAdd(&lc[dl], 1);
            stage[sc[dl] - h[dl] + r] = (int)(p >> BKB);
        }
        __syncthreads();
        for (int k = t; k < ecnt; k += 256) csr_src[ebase + k] = stage[k];
    } else {  // overflow fallback (never taken for this input)
        for (int k = t; k < ecnt; k += 256) {
            unsigned int p = ebuf[ebase + k];
            int dl = p & (BKS - 1);
            int r = atomicAdd(&lc[dl], 1);
            csr_src[ebase + sc[dl] - h[dl] + r] = (int)(p >> BKB);
        }
    }
}

// ------------------------------------------------- layer1 projection: X @ W1
__global__ __launch_bounds__(256) void k_proj1(const float* __restrict__ X,
                                               const float* __restrict__ W1,
                                               const int* __restrict__ cnt,
                                               float* __restrict__ hs1, int n) {
    __shared__ float Ws[IDIM * HID];
    for (int t = threadIdx.x; t < IDIM * HID; t += 256) Ws[t] = W1[t];
    __syncthreads();

    int i = blockIdx.x * blockDim.x + threadIdx.x;
    if (i >= n) return;

    const float4* xr = (const float4*)(X + (size_t)i * IDIM);
    float acc[HID];
#pragma unroll
    for (int j = 0; j < HID; ++j) acc[j] = 0.f;

    for (int k4 = 0; k4 < IDIM / 4; ++k4) {
        float4 x = xr[k4];
        const float* w = &Ws[k4 * 4 * HID];
#pragma unroll
        for (int j = 0; j < HID; ++j) acc[j] += x.x * w[j];
#pragma unroll
        for (int j = 0; j < HID; ++j) acc[j] += x.y * w[HID + j];
#pragma unroll
        for (int j = 0; j < HID; ++j) acc[j] += x.z * w[2 * HID + j];
#pragma unroll
        for (int j = 0; j < HID; ++j) acc[j] += x.w * w[3 * HID + j];
    }

    float di = rsqrtf((float)(cnt[i] + 1));
    float4* h4 = (float4*)(hs1 + (size_t)i * HID);
#pragma unroll
    for (int q = 0; q < 4; ++q) {
        float4 v;
        v.x = acc[q * 4 + 0] * di;
        v.y = acc[q * 4 + 1] * di;
        v.z = acc[q * 4 + 2] * di;
        v.w = acc[q * 4 + 3] * di;
        h4[q] = v;
    }
}

// ------------------------------------------- atomic-free aggregation via CSR
__global__ __launch_bounds__(256) void k_gather(const int* __restrict__ row_start,
                                                const int* __restrict__ cnt,
                                                const int* __restrict__ csr_src,
                                                const float* __restrict__ hs,
                                                float* __restrict__ agg, int n) {
    int tid = blockIdx.x * blockDim.x + threadIdx.x;
    int i = tid >> 2;
    int q = tid & 3;
    if (i >= n) return;
    int rs = row_start[i];
    int c = cnt[i];
    const float4* h4 = (const float4*)hs;
    float4 acc = h4[(size_t)i * 4 + q];  // self loop
    int k = 0;
    for (; k + 1 < c; k += 2) {
        int s0 = csr_src[rs + k];
        int s1 = csr_src[rs + k + 1];
        float4 v0 = h4[(size_t)s0 * 4 + q];
        float4 v1 = h4[(size_t)s1 * 4 + q];
        acc.x += v0.x; acc.y += v0.y; acc.z += v0.z; acc.w += v0.w;
        acc.x += v1.x; acc.y += v1.y; acc.z += v1.z; acc.w += v1.w;
    }
    if (k < c) {
        int s0 = csr_src[rs + k];
        float4 v0 = h4[(size_t)s0 * 4 + q];
        acc.x += v0.x; acc.y += v0.y; acc.z += v0.z; acc.w += v0.w;
    }
    ((float4*)agg)[(size_t)i * 4 + q] = acc;
}

// --------------------------- finalize L1 + rescale for L2 (in-place, per elem)
__global__ void k_mid(const int* __restrict__ cnt, const float* __restrict__ b1,
                      float* __restrict__ buf, int n) {
    int t = blockIdx.x * blockDim.x + threadIdx.x;
    if (t >= n * HID) return;
    int i = t >> 4;
    int j = t & 15;
    float di = rsqrtf((float)(cnt[i] + 1));
    float h = di * buf[t] + b1[j];
    h = fmaxf(h, 0.f);
    buf[t] = h * di;
}

// ----------------------------------------------- output projection g @ W2 + b
__global__ __launch_bounds__(256) void k_out(const int* __restrict__ cnt,
                                             const float* __restrict__ agg2,
                                             const float* __restrict__ W2,
                                             const float* __restrict__ b2,
                                             float* __restrict__ out, int n) {
    __shared__ float Ws[HID * ODIM];
    __shared__ float bs[ODIM];
    for (int t = threadIdx.x; t < HID * ODIM; t += 256) Ws[t] = W2[t];
    if (threadIdx.x < ODIM) bs[threadIdx.x] = b2[threadIdx.x];
    __syncthreads();

    int t = blockIdx.x * blockDim.x + threadIdx.x;
    if (t >= n * ODIM) return;
    int i = t >> 6;
    int j = t & 63;
    float di = rsqrtf((float)(cnt[i] + 1));
    const float* g = agg2 + (size_t)i * HID;
    float acc = 0.f;
#pragma unroll
    for (int k = 0; k < HID; ++k) acc += g[k] * Ws[k * ODIM + j];
    out[t] = di * acc + bs[j];
}

// ---------------------------------------------------------------------- launch
extern "C" void kernel_launch(void* const* d_in, const int* in_sizes, int n_in,
                              void* d_out, int out_size, void* d_ws, size_t ws_size,
                              hipStream_t stream) {
    const int* E = (const int*)d_in[1];
    const float* X = (const float*)d_in[2];
    const float* W1 = (const float*)d_in[3];
    const float* b1 = (const float*)d_in[4];
    const float* W2 = (const float*)d_in[5];
    const float* b2 = (const float*)d_in[6];
    float* out = (float*)d_out;

    const int n = in_sizes[0];       // 100000
    const int ne = in_sizes[1] / 2;  // 3200000
    const int* src = E;
    const int* dst = E + ne;
    const int nbk = (n + BKS - 1) >> BKB;  // 391

    // workspace layout (bytes):
    //   bcnt      @ 0     (2 KB)
    //   bbase     @ 8 KB
    //   bcur      @ 16 KB
    //   cnt       @ 1 MB  (400 KB)
    //   row_start @ 2 MB  (400 KB)
    //   ebuf      @ 3 MB  (12.8 MB)  [dead after k_csr; B1/B2 alias it]
    //   B1        @ 3 MB  (6.4 MB)
    //   B2        @ 10 MB (6.4 MB)
    //   csr_src   @ 17 MB (12.8 MB)   -> total 29.8 MB
    char* ws = (char*)d_ws;
    int* bcnt = (int*)ws;
    int* bbase = (int*)(ws + (8u << 10));
    int* bcur = (int*)(ws + (16u << 10));
    int* cnt = (int*)(ws + (1u << 20));
    int* row_start = (int*)(ws + (2u << 20));
    unsigned int* ebuf = (unsigned int*)(ws + (3u << 20));
    float* B1 = (float*)(ws + (3u << 20));
    float* B2 = (float*)(ws + (10u << 20));
    int* csr_src = (int*)(ws + (17u << 20));

    hipMemsetAsync(bcnt, 0, nbk * sizeof(int), stream);
    k_bhist<<<1024, 256, 0, stream>>>(dst, bcnt, ne, nbk);
    k_bscan<<<1, 512, 0, stream>>>(bcnt, bbase, bcur, nbk);
    k_part<<<(ne + PTILE - 1) / PTILE, 512, 0, stream>>>(src, dst, bcur, ebuf, ne, nbk);
    k_csr<<<nbk, 256, 0, stream>>>(bbase, bcnt, ebuf, cnt, row_start, csr_src, n);

    k_proj1<<<(n + 255) / 256, 256, 0, stream>>>(X, W1, cnt, B1, n);
    k_gather<<<(n * 4 + 255) / 256, 256, 0, stream>>>(row_start, cnt, csr_src, B1, B2, n);
    k_mid<<<(n * HID + 255) / 256, 256, 0, stream>>>(cnt, b1, B2, n);
    k_gather<<<(n * 4 + 255) / 256, 256, 0, stream>>>(row_start, cnt, csr_src, B2, B1, n);
    k_out<<<(n * ODIM + 255) / 256, 256, 0, stream>>>(cnt, B1, W2, b2, out, n);
}